// Round 7
// baseline (220.459 us; speedup 1.0000x reference)
//
#include <hip/hip_runtime.h>

// Flash-attention fwd, B=2,S=2048,H=16,D=128, logits = QK^T / D.
// Round 14: schedule levers on R13. R13 budget (6518 cyc/iter/CU): LDS 56%,
// VALU 37%, MFMA 33% -- no pipe saturated => chain/barrier limited.
// Changes vs R13 (layout & numerics untouched):
//  (1) BK=128: 4 kt-subtiles per barrier -> barriers 32->16, prefetch
//      window 2x, staging loop overhead halved. LDS = 139,264 B (ran fine
//      at this size in R10), still 1 block/CU, 8 waves (2/SIMD).
//      Key order preserved -> lsum/O accumulation order IDENTICAL to R13
//      (absmax must stay 4.883e-4).
//  (2) T5: s_setprio(1)/(0) around each MFMA cluster (QK, PV) -- measured
//      +4-7% on multi-wave attn (m191).
// Regs: kr[4]+vr[4] ~= +32 over R13's 80 -> ~112 < 128 cap, no spill.

#define SEQ   2048
#define NHEAD 16
#define DH    128
#define NB    2
#define BQ    256
#define BK    128
#define NTHR  512
#define KSTR  136   // ushorts per key row (128 d + 8 pad); 272B
#define VSTR  136   // ushorts per d row (128 keys + 8 pad); 272B
#define NKV   (SEQ / BK)
#define NELEM (NB * SEQ * NHEAD * DH)
#define KTILE (BK * KSTR)   // 17408 ushorts = 34,816 B
#define VTILE (DH * VSTR)   // 17408 ushorts = 34,816 B

typedef __attribute__((ext_vector_type(8)))  short bf16x8;
typedef __attribute__((ext_vector_type(16))) float f32x16;
typedef __attribute__((ext_vector_type(4)))  unsigned int u32x4;

__device__ __forceinline__ unsigned short f2bf(float x) {
    unsigned int u = __builtin_bit_cast(unsigned int, x);
    u += 0x7fffu + ((u >> 16) & 1u);
    return (unsigned short)(u >> 16);
}

// round-half-up to bf16; returns the bf16 value's fp32 bit pattern
__device__ __forceinline__ unsigned int bfr(float x) {
    unsigned int u = __builtin_bit_cast(unsigned int, x);
    return (u + 0x8000u) & 0xffff0000u;
}

// exchange: a.hi32lanes <-> b.lo32lanes  (v_permlane32_swap_b32)
__device__ __forceinline__ void pl32(unsigned int& a, unsigned int& b) {
    asm("v_permlane32_swap_b32 %0, %1" : "+v"(a), "+v"(b));
}

// ---- pass 1: fp32 -> bf16 (RNE), memory-bound
__global__ __launch_bounds__(256) void cvt_bf16(
    const float* __restrict__ q, const float* __restrict__ k,
    const float* __restrict__ v, unsigned short* __restrict__ dst)
{
    const int y = blockIdx.y;
    const float* s = (y == 0) ? q : (y == 1) ? k : v;
    unsigned short* d = dst + (size_t)y * NELEM;
    const int i = blockIdx.x * 256 + threadIdx.x;
    const float4 x = ((const float4*)s)[i];
    ushort4 o;
    o.x = f2bf(x.x); o.y = f2bf(x.y); o.z = f2bf(x.z); o.w = f2bf(x.w);
    ((ushort4*)d)[i] = o;
}

// ---- pass 2: attention
__global__ __launch_bounds__(NTHR, 2) void attn_fwd(
    const unsigned short* __restrict__ Qb,
    const unsigned short* __restrict__ Kb,
    const unsigned short* __restrict__ Vb,
    float* __restrict__ O)
{
    __shared__ unsigned short Kl[2][KTILE];   // 2 x 34,816 B
    __shared__ unsigned short Vl[2][VTILE];   // 2 x 34,816 B  [d][k]

    const int tid  = threadIdx.x;
    const int wave = tid >> 6;    // 0..7
    const int lane = tid & 63;
    const int hx   = lane >> 5;   // 0/1
    const int l32  = lane & 31;

    const int b  = blockIdx.y >> 4;
    const int h  = blockIdx.y & 15;
    const int q0 = blockIdx.x * BQ;

    const size_t rs = (size_t)NHEAD * DH;   // 2048 elems between seq rows
    const unsigned short* qb = Qb + (size_t)b * SEQ * rs + (size_t)h * DH;
    const unsigned short* kb = Kb + (size_t)b * SEQ * rs + (size_t)h * DH;
    const unsigned short* vb = Vb + (size_t)b * SEQ * rs + (size_t)h * DH;

    // ---- Q as B-operand frags: B[k=d][n=q], n=l32, k=(lane>>5)*8+j (+c*16)
    bf16x8 qf[8];
    {
        const unsigned short* qp = qb + (size_t)(q0 + wave * 32 + l32) * rs + hx * 8;
        #pragma unroll
        for (int c = 0; c < 8; ++c)
            qf[c] = *(const bf16x8*)(qp + c * 16);
    }

    // ---- staging maps (512 threads, BK=128)
    // K: 2048 16B-chunks (128 keys x 16 chunks): 4 per thread, coalesced.
    int kgo[4], kls[4];
    #pragma unroll
    for (int p = 0; p < 4; ++p) {
        const int cidx = p * NTHR + tid;
        const int key  = cidx >> 4;
        const int cc   = cidx & 15;
        kgo[p] = key * (int)rs + cc * 8;
        kls[p] = key * KSTR + cc * 8;
    }
    // V: key-pair kp (0..63) x d-chunk dcv (0..7, +8 on p=1).
    const int kp  = tid & 63;
    const int dcv = tid >> 6;   // 0..7

    f32x16 o4[4];
    #pragma unroll
    for (int t = 0; t < 4; ++t)
        #pragma unroll
        for (int r = 0; r < 16; ++r) o4[t][r] = 0.f;
    float lsum = 0.f;
    const float c1 = 1.44269504088896340736f / 128.0f;  // log2(e)/D

    bf16x8 kr[4], vr[4];

    // prologue: stage tile 0 into buffer 0
    {
        #pragma unroll
        for (int p = 0; p < 4; ++p) kr[p] = *(const bf16x8*)(kb + kgo[p]);
        #pragma unroll
        for (int p = 0; p < 2; ++p) {
            const unsigned short* src = vb + (size_t)(2 * kp) * rs + (dcv + p * 8) * 8;
            vr[p * 2]     = *(const bf16x8*)src;
            vr[p * 2 + 1] = *(const bf16x8*)(src + rs);
        }
        #pragma unroll
        for (int p = 0; p < 4; ++p) *(bf16x8*)&Kl[0][kls[p]] = kr[p];
        unsigned int* vw = (unsigned int*)&Vl[0][0];
        #pragma unroll
        for (int p = 0; p < 2; ++p)
            #pragma unroll
            for (int j = 0; j < 8; ++j) {
                const unsigned int pr = ((unsigned int)(unsigned short)vr[p * 2][j])
                                      | (((unsigned int)(unsigned short)vr[p * 2 + 1][j]) << 16);
                vw[((dcv + p * 8) * 8 + j) * (VSTR / 2) + kp] = pr;
            }
    }
    __syncthreads();

    for (int kv = 0; kv < NKV; ++kv) {
        const int cur = kv & 1;
        const int k0n = ((kv + 1) & (NKV - 1)) * BK;

        // ---- issue next tile's global loads (consumed after compute)
        #pragma unroll
        for (int p = 0; p < 4; ++p) kr[p] = *(const bf16x8*)(kb + (size_t)k0n * rs + kgo[p]);
        #pragma unroll
        for (int p = 0; p < 2; ++p) {
            const unsigned short* src = vb + (size_t)(k0n + 2 * kp) * rs + (dcv + p * 8) * 8;
            vr[p * 2]     = *(const bf16x8*)src;
            vr[p * 2 + 1] = *(const bf16x8*)(src + rs);
        }

        const unsigned short* Kc = &Kl[cur][0];
        const unsigned short* Vc = &Vl[cur][0];

        #pragma unroll
        for (int kt = 0; kt < 4; ++kt) {
            // ---- S^T(32 keys x 32 q) = K * Q^T
            f32x16 s;
            #pragma unroll
            for (int r = 0; r < 16; ++r) s[r] = 0.f;
            __builtin_amdgcn_s_setprio(1);
            #pragma unroll
            for (int c = 0; c < 8; ++c) {
                bf16x8 kf = *(const bf16x8*)&Kc[(kt * 32 + l32) * KSTR + c * 16 + hx * 8];
                s = __builtin_amdgcn_mfma_f32_32x32x16_bf16(kf, qf[c], s, 0, 0, 0);
            }
            __builtin_amdgcn_s_setprio(0);

            // ---- exp2(s*c1), round to bf16 ONCE; lsum accumulates the
            // ROUNDED values (O/L consistency). lane holds
            // P[q=l32][key=(r&3)+8*(r>>2)+4*hx]; w[g][p]=keys(8g+4hx+2p,+1).
            unsigned int w[4][2];
            #pragma unroll
            for (int g = 0; g < 4; ++g) {
                const unsigned int u0 = bfr(__builtin_amdgcn_exp2f(s[g * 4 + 0] * c1));
                const unsigned int u1 = bfr(__builtin_amdgcn_exp2f(s[g * 4 + 1] * c1));
                const unsigned int u2 = bfr(__builtin_amdgcn_exp2f(s[g * 4 + 2] * c1));
                const unsigned int u3 = bfr(__builtin_amdgcn_exp2f(s[g * 4 + 3] * c1));
                lsum += (__builtin_bit_cast(float, u0) + __builtin_bit_cast(float, u1))
                      + (__builtin_bit_cast(float, u2) + __builtin_bit_cast(float, u3));
                w[g][0] = u1 | (u0 >> 16);
                w[g][1] = u3 | (u2 >> 16);
            }

            // ---- lane l <-> l+32 half-exchange -> PV A-frags in registers
            #pragma unroll
            for (int ks = 0; ks < 2; ++ks) {
                pl32(w[2 * ks][0], w[2 * ks + 1][0]);
                pl32(w[2 * ks][1], w[2 * ks + 1][1]);
            }
            bf16x8 pf[2];
            #pragma unroll
            for (int ks = 0; ks < 2; ++ks) {
                u32x4 t;
                t.x = w[2 * ks][0];
                t.y = w[2 * ks][1];
                t.z = w[2 * ks + 1][0];
                t.w = w[2 * ks + 1][1];
                pf[ks] = __builtin_bit_cast(bf16x8, t);
            }

            // ---- O += P V for this key-subtile (wave-private, no barrier)
            __builtin_amdgcn_s_setprio(1);
            #pragma unroll
            for (int ks = 0; ks < 2; ++ks)
                #pragma unroll
                for (int dt = 0; dt < 4; ++dt) {
                    bf16x8 vf = *(const bf16x8*)&Vc[(dt * 32 + l32) * VSTR
                                                    + kt * 32 + ks * 16 + hx * 8];
                    o4[dt] = __builtin_amdgcn_mfma_f32_32x32x16_bf16(pf[ks], vf, o4[dt], 0, 0, 0);
                }
            __builtin_amdgcn_s_setprio(0);
        }

        // ---- write staged next tile into the other buffer
        const int nxt = cur ^ 1;
        #pragma unroll
        for (int p = 0; p < 4; ++p) *(bf16x8*)&Kl[nxt][kls[p]] = kr[p];
        {
            unsigned int* vw = (unsigned int*)&Vl[nxt][0];
            #pragma unroll
            for (int p = 0; p < 2; ++p)
                #pragma unroll
                for (int j = 0; j < 8; ++j) {
                    const unsigned int pr = ((unsigned int)(unsigned short)vr[p * 2][j])
                                          | (((unsigned int)(unsigned short)vr[p * 2 + 1][j]) << 16);
                    vw[((dcv + p * 8) * 8 + j) * (VSTR / 2) + kp] = pr;
                }
        }
        __syncthreads();
    }

    // ---- epilogue: L per q, then normalize + store (coalesced 128B runs)
    lsum += __shfl_xor(lsum, 32, 64);
    const float inv = 1.0f / lsum;     // valid for q = l32 (both halves)
    float iv[16];
    #pragma unroll
    for (int r = 0; r < 16; ++r)
        iv[r] = __shfl(inv, (r & 3) + 8 * (r >> 2) + 4 * hx, 64);

    #pragma unroll
    for (int dt = 0; dt < 4; ++dt) {
        #pragma unroll
        for (int r = 0; r < 16; ++r) {
            const int ql = (r & 3) + 8 * (r >> 2) + 4 * hx;
            const int qg = q0 + wave * 32 + ql;
            O[(size_t)(b * SEQ + qg) * rs + (size_t)h * DH + dt * 32 + l32] = o4[dt][r] * iv[r];
        }
    }
}

extern "C" void kernel_launch(void* const* d_in, const int* in_sizes, int n_in,
                              void* d_out, int out_size, void* d_ws, size_t ws_size,
                              hipStream_t stream) {
    const float* q = (const float*)d_in[0];
    const float* k = (const float*)d_in[1];
    const float* v = (const float*)d_in[2];
    float* o = (float*)d_out;
    unsigned short* wsb = (unsigned short*)d_ws;

    cvt_bf16<<<dim3(NELEM / 1024, 3), 256, 0, stream>>>(q, k, v, wsb);
    attn_fwd<<<dim3(SEQ / BQ, NB * NHEAD), dim3(NTHR), 0, stream>>>(
        wsb, wsb + NELEM, wsb + 2 * (size_t)NELEM, o);
}

// Round 8
// 211.639 us; speedup vs baseline: 1.0417x; 1.0417x over previous
//
#include <hip/hip_runtime.h>

// Flash-attention fwd, B=2,S=2048,H=16,D=128, logits = QK^T / D.
// Round 15: R13 base + ONE lever (R14's BK=128+setprio bundle regressed 12%
// -- both reverted). R13 budget: LDS 3800 / VALU 2400 / MFMA 2066 cyc per
// iter/CU vs 6518 measured => ~2700 cyc exposed QK->exp2->PV serial chain
// (in-order issue: matrix pipe idles during softmax, VALU during MFMA).
// Lever (T15, m214 v36 +7-11% on this exact structure): explicit 2-tile
// pipeline per iteration -- QK0 -> QK1 -> SM0 -> SM1 -> PV0 -> PV1 with
// fully static named registers (s0/s1, w0/w1, pf0/pf1). QK1 is independent
// of SM0, PV0 independent of SM1 -> scheduler interleaves VALU into MFMA
// clusters. lsum order unchanged (P0 adds then P1) => absmax bit-identical.
// Everything else byte-identical to R13 (staging dedup, permlane P path,
// consistent O/L bfr rounding, BQ=256/BK=64, 512 thr, LDS 71,680B).

#define SEQ   2048
#define NHEAD 16
#define DH    128
#define NB    2
#define BQ    256
#define BK    64
#define NTHR  512
#define KSTR  136   // ushorts; 272B row; conflict-free for 32-lane frag reads
#define VSTR  72    // ushorts; 144B row
#define NKV   (SEQ / BK)
#define NELEM (NB * SEQ * NHEAD * DH)
#define KTILE (BK * KSTR)   // 8704 ushorts
#define VTILE (DH * VSTR)   // 9216 ushorts

typedef __attribute__((ext_vector_type(8)))  short bf16x8;
typedef __attribute__((ext_vector_type(16))) float f32x16;
typedef __attribute__((ext_vector_type(4)))  unsigned int u32x4;

__device__ __forceinline__ unsigned short f2bf(float x) {
    unsigned int u = __builtin_bit_cast(unsigned int, x);
    u += 0x7fffu + ((u >> 16) & 1u);
    return (unsigned short)(u >> 16);
}

// round-half-up to bf16; returns the bf16 value's fp32 bit pattern
__device__ __forceinline__ unsigned int bfr(float x) {
    unsigned int u = __builtin_bit_cast(unsigned int, x);
    return (u + 0x8000u) & 0xffff0000u;
}

// exchange: a.hi32lanes <-> b.lo32lanes  (v_permlane32_swap_b32)
__device__ __forceinline__ void pl32(unsigned int& a, unsigned int& b) {
    asm("v_permlane32_swap_b32 %0, %1" : "+v"(a), "+v"(b));
}

// ---- pass 1: fp32 -> bf16 (RNE), memory-bound
__global__ __launch_bounds__(256) void cvt_bf16(
    const float* __restrict__ q, const float* __restrict__ k,
    const float* __restrict__ v, unsigned short* __restrict__ dst)
{
    const int y = blockIdx.y;
    const float* s = (y == 0) ? q : (y == 1) ? k : v;
    unsigned short* d = dst + (size_t)y * NELEM;
    const int i = blockIdx.x * 256 + threadIdx.x;
    const float4 x = ((const float4*)s)[i];
    ushort4 o;
    o.x = f2bf(x.x); o.y = f2bf(x.y); o.z = f2bf(x.z); o.w = f2bf(x.w);
    ((ushort4*)d)[i] = o;
}

// ---- pass 2: attention
__global__ __launch_bounds__(NTHR, 2) void attn_fwd(
    const unsigned short* __restrict__ Qb,
    const unsigned short* __restrict__ Kb,
    const unsigned short* __restrict__ Vb,
    float* __restrict__ O)
{
    __shared__ unsigned short Kl[2][KTILE];   // 2 x 17,408 B
    __shared__ unsigned short Vl[2][VTILE];   // 2 x 18,432 B  [d][k]

    const int tid  = threadIdx.x;
    const int wave = tid >> 6;    // 0..7
    const int lane = tid & 63;
    const int hx   = lane >> 5;   // 0/1
    const int l32  = lane & 31;

    const int b  = blockIdx.y >> 4;
    const int h  = blockIdx.y & 15;
    const int q0 = blockIdx.x * BQ;

    const size_t rs = (size_t)NHEAD * DH;   // 2048 elems between seq rows
    const unsigned short* qb = Qb + (size_t)b * SEQ * rs + (size_t)h * DH;
    const unsigned short* kb = Kb + (size_t)b * SEQ * rs + (size_t)h * DH;
    const unsigned short* vb = Vb + (size_t)b * SEQ * rs + (size_t)h * DH;

    // ---- Q as B-operand frags: B[k=d][n=q], n=l32, k=(lane>>5)*8+j (+c*16)
    bf16x8 qf[8];
    {
        const unsigned short* qp = qb + (size_t)(q0 + wave * 32 + l32) * rs + hx * 8;
        #pragma unroll
        for (int c = 0; c < 8; ++c)
            qf[c] = *(const bf16x8*)(qp + c * 16);
    }

    // ---- staging maps (512 threads; same as R13)
    // K: 1024 16B-chunks (64 keys x 16 chunks): 2 per thread, coalesced.
    int kgo[2], kls[2];
    #pragma unroll
    for (int p = 0; p < 2; ++p) {
        const int cidx = p * NTHR + tid;
        const int key  = cidx >> 4;
        const int cc   = cidx & 15;
        kgo[p] = key * (int)rs + cc * 8;
        kls[p] = key * KSTR + cc * 8;
    }
    // V: key-pair kp (0..31) x d-chunk dcv (0..15): 1 (pair, chunk) per thread.
    const int kp  = tid & 31;
    const int dcv = tid >> 5;   // 0..15

    f32x16 o4[4];
    #pragma unroll
    for (int t = 0; t < 4; ++t)
        #pragma unroll
        for (int r = 0; r < 16; ++r) o4[t][r] = 0.f;
    float lsum = 0.f;
    const float c1 = 1.44269504088896340736f / 128.0f;  // log2(e)/D

    bf16x8 kr[2], vr[2];

    // prologue: stage tile 0 into buffer 0
    {
        #pragma unroll
        for (int p = 0; p < 2; ++p) kr[p] = *(const bf16x8*)(kb + kgo[p]);
        {
            const unsigned short* src = vb + (size_t)(2 * kp) * rs + dcv * 8;
            vr[0] = *(const bf16x8*)src;
            vr[1] = *(const bf16x8*)(src + rs);
        }
        #pragma unroll
        for (int p = 0; p < 2; ++p) *(bf16x8*)&Kl[0][kls[p]] = kr[p];
        unsigned int* vw = (unsigned int*)&Vl[0][0];
        #pragma unroll
        for (int j = 0; j < 8; ++j) {
            const unsigned int pr = ((unsigned int)(unsigned short)vr[0][j])
                                  | (((unsigned int)(unsigned short)vr[1][j]) << 16);
            vw[(dcv * 8 + j) * (VSTR / 2) + kp] = pr;
        }
    }
    __syncthreads();

    for (int kv = 0; kv < NKV; ++kv) {
        const int cur = kv & 1;
        const int k0n = ((kv + 1) & (NKV - 1)) * BK;

        // ---- issue next tile's global loads (consumed after compute)
        #pragma unroll
        for (int p = 0; p < 2; ++p) kr[p] = *(const bf16x8*)(kb + (size_t)k0n * rs + kgo[p]);
        {
            const unsigned short* src = vb + (size_t)(k0n + 2 * kp) * rs + dcv * 8;
            vr[0] = *(const bf16x8*)src;
            vr[1] = *(const bf16x8*)(src + rs);
        }

        const unsigned short* Kc = &Kl[cur][0];
        const unsigned short* Vc = &Vl[cur][0];

        // ================= pipelined kt-pair =================
        // QK0: S^T(keys 0..31 x 32 q) = K * Q^T
        f32x16 s0, s1;
        #pragma unroll
        for (int r = 0; r < 16; ++r) { s0[r] = 0.f; s1[r] = 0.f; }
        #pragma unroll
        for (int c = 0; c < 8; ++c) {
            bf16x8 kf = *(const bf16x8*)&Kc[(l32) * KSTR + c * 16 + hx * 8];
            s0 = __builtin_amdgcn_mfma_f32_32x32x16_bf16(kf, qf[c], s0, 0, 0, 0);
        }
        // QK1: independent of SM0 -> scheduler interleaves SM0's VALU below
        #pragma unroll
        for (int c = 0; c < 8; ++c) {
            bf16x8 kf = *(const bf16x8*)&Kc[(32 + l32) * KSTR + c * 16 + hx * 8];
            s1 = __builtin_amdgcn_mfma_f32_32x32x16_bf16(kf, qf[c], s1, 0, 0, 0);
        }

        // SM0: exp2(s0*c1), bf16 half-up round ONCE; lsum += rounded values.
        // lane holds P[q=l32][key=(r&3)+8*(r>>2)+4*hx]; w[g][p]=keys(8g+4hx+2p,+1).
        unsigned int w0[4][2], w1[4][2];
        #pragma unroll
        for (int g = 0; g < 4; ++g) {
            const unsigned int u0 = bfr(__builtin_amdgcn_exp2f(s0[g * 4 + 0] * c1));
            const unsigned int u1 = bfr(__builtin_amdgcn_exp2f(s0[g * 4 + 1] * c1));
            const unsigned int u2 = bfr(__builtin_amdgcn_exp2f(s0[g * 4 + 2] * c1));
            const unsigned int u3 = bfr(__builtin_amdgcn_exp2f(s0[g * 4 + 3] * c1));
            lsum += (__builtin_bit_cast(float, u0) + __builtin_bit_cast(float, u1))
                  + (__builtin_bit_cast(float, u2) + __builtin_bit_cast(float, u3));
            w0[g][0] = u1 | (u0 >> 16);
            w0[g][1] = u3 | (u2 >> 16);
        }
        // SM1 (independent of PV0)
        #pragma unroll
        for (int g = 0; g < 4; ++g) {
            const unsigned int u0 = bfr(__builtin_amdgcn_exp2f(s1[g * 4 + 0] * c1));
            const unsigned int u1 = bfr(__builtin_amdgcn_exp2f(s1[g * 4 + 1] * c1));
            const unsigned int u2 = bfr(__builtin_amdgcn_exp2f(s1[g * 4 + 2] * c1));
            const unsigned int u3 = bfr(__builtin_amdgcn_exp2f(s1[g * 4 + 3] * c1));
            lsum += (__builtin_bit_cast(float, u0) + __builtin_bit_cast(float, u1))
                  + (__builtin_bit_cast(float, u2) + __builtin_bit_cast(float, u3));
            w1[g][0] = u1 | (u0 >> 16);
            w1[g][1] = u3 | (u2 >> 16);
        }

        // permlane half-exchanges -> PV A-frags (static names)
        bf16x8 pf0[2], pf1[2];
        #pragma unroll
        for (int ks = 0; ks < 2; ++ks) {
            pl32(w0[2 * ks][0], w0[2 * ks + 1][0]);
            pl32(w0[2 * ks][1], w0[2 * ks + 1][1]);
            u32x4 t;
            t.x = w0[2 * ks][0];
            t.y = w0[2 * ks][1];
            t.z = w0[2 * ks + 1][0];
            t.w = w0[2 * ks + 1][1];
            pf0[ks] = __builtin_bit_cast(bf16x8, t);
        }
        #pragma unroll
        for (int ks = 0; ks < 2; ++ks) {
            pl32(w1[2 * ks][0], w1[2 * ks + 1][0]);
            pl32(w1[2 * ks][1], w1[2 * ks + 1][1]);
            u32x4 t;
            t.x = w1[2 * ks][0];
            t.y = w1[2 * ks][1];
            t.z = w1[2 * ks + 1][0];
            t.w = w1[2 * ks + 1][1];
            pf1[ks] = __builtin_bit_cast(bf16x8, t);
        }

        // PV0: O += P0 V(keys 0..31)
        #pragma unroll
        for (int ks = 0; ks < 2; ++ks)
            #pragma unroll
            for (int dt = 0; dt < 4; ++dt) {
                bf16x8 vf = *(const bf16x8*)&Vc[(dt * 32 + l32) * VSTR
                                                + ks * 16 + hx * 8];
                o4[dt] = __builtin_amdgcn_mfma_f32_32x32x16_bf16(pf0[ks], vf, o4[dt], 0, 0, 0);
            }
        // PV1: O += P1 V(keys 32..63)
        #pragma unroll
        for (int ks = 0; ks < 2; ++ks)
            #pragma unroll
            for (int dt = 0; dt < 4; ++dt) {
                bf16x8 vf = *(const bf16x8*)&Vc[(dt * 32 + l32) * VSTR
                                                + 32 + ks * 16 + hx * 8];
                o4[dt] = __builtin_amdgcn_mfma_f32_32x32x16_bf16(pf1[ks], vf, o4[dt], 0, 0, 0);
            }
        // =====================================================

        // ---- write staged next tile into the other buffer
        const int nxt = cur ^ 1;
        #pragma unroll
        for (int p = 0; p < 2; ++p) *(bf16x8*)&Kl[nxt][kls[p]] = kr[p];
        {
            unsigned int* vw = (unsigned int*)&Vl[nxt][0];
            #pragma unroll
            for (int j = 0; j < 8; ++j) {
                const unsigned int pr = ((unsigned int)(unsigned short)vr[0][j])
                                      | (((unsigned int)(unsigned short)vr[1][j]) << 16);
                vw[(dcv * 8 + j) * (VSTR / 2) + kp] = pr;
            }
        }
        __syncthreads();
    }

    // ---- epilogue: L per q, then normalize + store (coalesced 128B runs)
    lsum += __shfl_xor(lsum, 32, 64);
    const float inv = 1.0f / lsum;     // valid for q = l32 (both halves)
    float iv[16];
    #pragma unroll
    for (int r = 0; r < 16; ++r)
        iv[r] = __shfl(inv, (r & 3) + 8 * (r >> 2) + 4 * hx, 64);

    #pragma unroll
    for (int dt = 0; dt < 4; ++dt) {
        #pragma unroll
        for (int r = 0; r < 16; ++r) {
            const int ql = (r & 3) + 8 * (r >> 2) + 4 * hx;
            const int qg = q0 + wave * 32 + ql;
            O[(size_t)(b * SEQ + qg) * rs + (size_t)h * DH + dt * 32 + l32] = o4[dt][r] * iv[r];
        }
    }
}

extern "C" void kernel_launch(void* const* d_in, const int* in_sizes, int n_in,
                              void* d_out, int out_size, void* d_ws, size_t ws_size,
                              hipStream_t stream) {
    const float* q = (const float*)d_in[0];
    const float* k = (const float*)d_in[1];
    const float* v = (const float*)d_in[2];
    float* o = (float*)d_out;
    unsigned short* wsb = (unsigned short*)d_ws;

    cvt_bf16<<<dim3(NELEM / 1024, 3), 256, 0, stream>>>(q, k, v, wsb);
    attn_fwd<<<dim3(SEQ / BQ, NB * NHEAD), dim3(NTHR), 0, stream>>>(
        wsb, wsb + NELEM, wsb + 2 * (size_t)NELEM, o);
}